// Round 2
// baseline (339.202 us; speedup 1.0000x reference)
//
#include <hip/hip_runtime.h>

#define B_SZ 4096
#define S_SZ 128
#define XD 5
#define EH 128
#define DH 256
#define DSTEPS 10

typedef short v8s __attribute__((ext_vector_type(8)));
typedef float v4f __attribute__((ext_vector_type(4)));

__device__ __forceinline__ float bf2f(unsigned short u) {
    union { unsigned int i; float f; } v; v.i = ((unsigned int)u) << 16; return v.f;
}
__device__ __forceinline__ unsigned short f2bf(float f) {
    union { float f; unsigned int i; } v; v.f = f;
    unsigned int x = v.i;
    return (unsigned short)((x + 0x7FFFu + ((x >> 16) & 1u)) >> 16);
}
__device__ __forceinline__ float fexp2(float x) { return __builtin_amdgcn_exp2f(x); }
__device__ __forceinline__ float frcp(float x) { return __builtin_amdgcn_rcpf(x); }
__device__ __forceinline__ float sigmoidf_(float x) {
    return frcp(1.f + fexp2(-1.44269504088896f * x));
}
__device__ __forceinline__ float tanhf_(float x) {
    float e = fexp2(2.88539008177793f * x);   // e^(2x)
    return 1.f - 2.f * frcp(e + 1.f);
}

// ---------------------------------------------------------------- prep
// Converts fp32 weights -> bf16 workspace copies, inits hist0=1, pads out.
__global__ void prep_kernel(const float* __restrict__ dWih,   // [768][129]
                            const float* __restrict__ eWhh,   // [384][128]
                            const float* __restrict__ eWih,   // [384][5]
                            const float* __restrict__ dWhh,   // [768][256]
                            unsigned short* __restrict__ wihp,     // [768][136] bf16
                            unsigned short* __restrict__ eWhh_bf,  // [384][128] bf16
                            unsigned short* __restrict__ eWih_bf,  // [384][5]  bf16
                            unsigned short* __restrict__ dWhh_bf,  // [768][256] bf16
                            unsigned short* __restrict__ hist0,    // [B][256] bf16
                            float* __restrict__ out)               // [B][S][4] fp32
{
    const unsigned short ONE = 0x3F80;
    const int NW  = 768 * 136;      // wihp
    const int NE1 = 384 * 128;      // eWhh
    const int NE2 = 384 * 5;        // eWih
    const int ND  = 768 * 256;      // dWhh
    const int NH  = B_SZ * DH;      // hist0
    const int NO  = B_SZ * S_SZ * 4;
    const int total = NW + NE1 + NE2 + ND + NH + NO;
    for (int i = blockIdx.x * 256 + threadIdx.x; i < total; i += gridDim.x * 256) {
        int idx = i;
        if (idx < NW) {
            int col = idx / 136, k = idx - col * 136;
            wihp[idx] = (k < 129) ? f2bf(dWih[col * 129 + k]) : (unsigned short)0;
            continue;
        }
        idx -= NW;
        if (idx < NE1) { eWhh_bf[idx] = f2bf(eWhh[idx]); continue; }
        idx -= NE1;
        if (idx < NE2) { eWih_bf[idx] = f2bf(eWih[idx]); continue; }
        idx -= NE2;
        if (idx < ND)  { dWhh_bf[idx] = f2bf(dWhh[idx]); continue; }
        idx -= ND;
        if (idx < NH)  { hist0[idx] = ONE; continue; }
        idx -= NH;
        int s = (idx >> 2) & (S_SZ - 1);
        if (s >= DSTEPS) out[idx] = 1.0f;
    }
}

// ---------------------------------------------------------------- encoder
// 256 blocks x 512 threads. Block owns 16 batch rows; 8 waves each own a
// 16-col chunk of all 3 gates. Whh/Wih B-frags held in VGPRs for all 128
// steps; h ping-pongs through LDS (bf16); state kept fp32 in registers.
__global__ __launch_bounds__(512) void enc_kernel(
    const float* __restrict__ x,              // [B][S][5] fp32
    const unsigned short* __restrict__ Wih,   // [384][5]  bf16
    const unsigned short* __restrict__ Whh,   // [384][128] bf16
    const float* __restrict__ bih,            // [384] fp32
    const float* __restrict__ bhh,            // [384] fp32
    unsigned short* __restrict__ ctex)        // [B][128] bf16
{
    __shared__ unsigned short xs[S_SZ][16][8];     // 32 KB
    __shared__ unsigned short hb[2][16][136];      // 8.5 KB, +8 pad
    __shared__ unsigned short zpad[8];

    const int tid = threadIdx.x;
    const int wv = tid >> 6;
    const int lane = tid & 63;
    const int n = lane & 15;
    const int kg = lane >> 4;       // K-group / C-row quad
    const int r0 = blockIdx.x * 16;

    for (int i = tid; i < 2 * 16 * 136; i += 512) ((unsigned short*)hb)[i] = 0;
    if (tid < 8) zpad[tid] = 0;
    for (int i = tid; i < 16 * S_SZ * 8; i += 512) {
        int m = i >> 10;            // / (128*8)
        int rem = i & 1023;
        int t = rem >> 3;
        int j = rem & 7;
        unsigned short v = 0;
        if (j < XD) v = f2bf(x[(size_t)(r0 + m) * (S_SZ * XD) + t * XD + j]);
        xs[t][m][j] = v;
    }

    const int colw = wv * 16 + n;   // this lane's column within H
    v8s fw[3][4];                   // Whh B-frags [gate][K-tile]
    v8s fx[3];                      // Wih B-frags [gate]
    #pragma unroll
    for (int g = 0; g < 3; ++g) {
        int gcol = g * EH + colw;
        #pragma unroll
        for (int kt = 0; kt < 4; ++kt)
            fw[g][kt] = *(const v8s*)&Whh[gcol * EH + kt * 32 + kg * 8];
        v8s t = {0, 0, 0, 0, 0, 0, 0, 0};
        if (kg == 0) {
            const unsigned short* p = &Wih[gcol * XD];
            #pragma unroll
            for (int j = 0; j < XD; ++j) t[j] = (short)p[j];
        }
        fx[g] = t;
    }
    const float b_r  = bih[colw]          + bhh[colw];
    const float b_z  = bih[EH + colw]     + bhh[EH + colw];
    const float bi_n = bih[2 * EH + colw];
    const float bh_n = bhh[2 * EH + colw];

    float hst[4] = {0.f, 0.f, 0.f, 0.f};
    __syncthreads();

    #pragma unroll 2
    for (int t = 0; t < S_SZ; ++t) {
        const int p = t & 1;
        v8s a[4];
        #pragma unroll
        for (int kt = 0; kt < 4; ++kt)
            a[kt] = *(const v8s*)&hb[p][n][kt * 32 + kg * 8];
        const unsigned short* xsrc = (kg == 0) ? &xs[t][n][0] : &zpad[0];
        v8s ax = *(const v8s*)xsrc;

        v4f accr  = {b_r, b_r, b_r, b_r};
        v4f accz  = {b_z, b_z, b_z, b_z};
        v4f acchn = {bh_n, bh_n, bh_n, bh_n};
        v4f accin = {bi_n, bi_n, bi_n, bi_n};
        #pragma unroll
        for (int kt = 0; kt < 4; ++kt) {
            accr  = __builtin_amdgcn_mfma_f32_16x16x32_bf16(a[kt], fw[0][kt], accr, 0, 0, 0);
            accz  = __builtin_amdgcn_mfma_f32_16x16x32_bf16(a[kt], fw[1][kt], accz, 0, 0, 0);
            acchn = __builtin_amdgcn_mfma_f32_16x16x32_bf16(a[kt], fw[2][kt], acchn, 0, 0, 0);
        }
        accr  = __builtin_amdgcn_mfma_f32_16x16x32_bf16(ax, fx[0], accr, 0, 0, 0);
        accz  = __builtin_amdgcn_mfma_f32_16x16x32_bf16(ax, fx[1], accz, 0, 0, 0);
        accin = __builtin_amdgcn_mfma_f32_16x16x32_bf16(ax, fx[2], accin, 0, 0, 0);

        #pragma unroll
        for (int e = 0; e < 4; ++e) {
            float r = sigmoidf_(accr[e]);
            float z = sigmoidf_(accz[e]);
            float nn = tanhf_(accin[e] + r * acchn[e]);
            float h = (1.f - z) * nn + z * hst[e];
            hst[e] = h;
            hb[1 - p][kg * 4 + e][colw] = f2bf(h);
        }
        __syncthreads();
    }
    #pragma unroll
    for (int e = 0; e < 4; ++e)
        ctex[(size_t)(r0 + kg * 4 + e) * EH + colw] = f2bf(hst[e]);
}

// ---------------------------------------------------------------- gi_base
// gib[b][768] = contex @ dec_Wih[:, :128].T + dec_bih   (bf16 out)
__global__ __launch_bounds__(256) void gib_kernel(
    const unsigned short* __restrict__ ctex,   // [B][128] bf16
    const unsigned short* __restrict__ wihp,   // [768][136] bf16
    const float* __restrict__ dbih,            // [768] fp32
    unsigned short* __restrict__ gib)          // [B][768] bf16
{
    const int tid = threadIdx.x;
    const int wv = tid >> 6, lane = tid & 63, n = lane & 15, kg = lane >> 4;
    const int rb = blockIdx.x * 64 + wv * 16;
    const int cb = blockIdx.y * 64;

    v8s a[4];
    #pragma unroll
    for (int kt = 0; kt < 4; ++kt)
        a[kt] = *(const v8s*)&ctex[(size_t)(rb + n) * EH + kt * 32 + kg * 8];

    #pragma unroll
    for (int nt = 0; nt < 4; ++nt) {
        int col = cb + nt * 16 + n;
        float bb = dbih[col];
        v4f acc = {bb, bb, bb, bb};
        #pragma unroll
        for (int kt = 0; kt < 4; ++kt) {
            v8s b = *(const v8s*)&wihp[col * 136 + kt * 32 + kg * 8];
            acc = __builtin_amdgcn_mfma_f32_16x16x32_bf16(a[kt], b, acc, 0, 0, 0);
        }
        #pragma unroll
        for (int e = 0; e < 4; ++e)
            gib[(size_t)(rb + kg * 4 + e) * 768 + col] = f2bf(acc[e]);
    }
}

// ---------------------------------------------------------------- decoder step
// grid (32, 8): M=128 rows/block, 32 cols per gate per block (chunk).
// Whh chunk (96 rows x 256 K bf16 = 48KB) staged in LDS, shared by 4 waves.
__global__ __launch_bounds__(256) void dec_kernel(
    const unsigned short* __restrict__ dWhh,   // [768][256] bf16
    const float* __restrict__ dWih,            // [768][129] fp32 (col 128 = y weight)
    const float* __restrict__ dbhh,            // [768] fp32
    const float* __restrict__ y,               // [B][128] fp32
    const unsigned short* __restrict__ gib,    // [B][768] bf16
    const unsigned short* __restrict__ histp,  // h_t   [B][256] bf16
    unsigned short* __restrict__ histn,        // h_t+1 [B][256] bf16
    int t)
{
    __shared__ unsigned short wsh[96][264];    // +8 pad
    const int tid = threadIdx.x;
    const int wv = tid >> 6, lane = tid & 63, n = lane & 15, kg = lane >> 4;
    const int rb = blockIdx.x * 128;
    const int cb = blockIdx.y * 32;
    const int rw = rb + wv * 32;

    for (int cid = tid; cid < 96 * 32; cid += 256) {
        int lr = cid >> 5;
        int off = (cid & 31) * 8;
        int grow = (lr >> 5) * DH + cb + (lr & 31);
        *(uint4*)&wsh[lr][off] = *(const uint4*)&dWhh[(size_t)grow * DH + off];
    }
    __syncthreads();

    float bR[2], bZ[2], bN[2], wyR[2], wyZ[2], wyN[2];
    #pragma unroll
    for (int ct = 0; ct < 2; ++ct) {
        int lc = cb + ct * 16 + n;
        bR[ct] = dbhh[lc];
        bZ[ct] = dbhh[DH + lc];
        bN[ct] = dbhh[2 * DH + lc];
        wyR[ct] = dWih[(size_t)lc * 129 + 128];
        wyZ[ct] = dWih[(size_t)(DH + lc) * 129 + 128];
        wyN[ct] = dWih[(size_t)(2 * DH + lc) * 129 + 128];
    }

    v4f acc[3][2][2];   // [gate][ct][mt]
    #pragma unroll
    for (int g = 0; g < 3; ++g)
        #pragma unroll
        for (int ct = 0; ct < 2; ++ct) {
            float bb = (g == 0) ? bR[ct] : ((g == 1) ? bZ[ct] : bN[ct]);
            acc[g][ct][0] = (v4f){bb, bb, bb, bb};
            acc[g][ct][1] = (v4f){bb, bb, bb, bb};
        }

    for (int kt = 0; kt < 8; ++kt) {
        v8s a0 = *(const v8s*)&histp[(size_t)(rw + n) * DH + kt * 32 + kg * 8];
        v8s a1 = *(const v8s*)&histp[(size_t)(rw + 16 + n) * DH + kt * 32 + kg * 8];
        #pragma unroll
        for (int g = 0; g < 3; ++g)
            #pragma unroll
            for (int ct = 0; ct < 2; ++ct) {
                v8s b = *(const v8s*)&wsh[g * 32 + ct * 16 + n][kt * 32 + kg * 8];
                acc[g][ct][0] = __builtin_amdgcn_mfma_f32_16x16x32_bf16(a0, b, acc[g][ct][0], 0, 0, 0);
                acc[g][ct][1] = __builtin_amdgcn_mfma_f32_16x16x32_bf16(a1, b, acc[g][ct][1], 0, 0, 0);
            }
    }

    #pragma unroll
    for (int mt = 0; mt < 2; ++mt)
        #pragma unroll
        for (int ct = 0; ct < 2; ++ct) {
            int lc = cb + ct * 16 + n;
            #pragma unroll
            for (int e = 0; e < 4; ++e) {
                int row = rw + mt * 16 + kg * 4 + e;
                float yv = y[(size_t)row * S_SZ + t];
                float giR = bf2f(gib[(size_t)row * 768 + lc]) + yv * wyR[ct];
                float giZ = bf2f(gib[(size_t)row * 768 + DH + lc]) + yv * wyZ[ct];
                float giN = bf2f(gib[(size_t)row * 768 + 2 * DH + lc]) + yv * wyN[ct];
                float r = sigmoidf_(giR + acc[0][ct][mt][e]);
                float z = sigmoidf_(giZ + acc[1][ct][mt][e]);
                float nn = tanhf_(giN + r * acc[2][ct][mt][e]);
                float hold = bf2f(histp[(size_t)row * DH + lc]);
                float h = (1.f - z) * nn + z * hold;
                histn[(size_t)row * DH + lc] = f2bf(h);
            }
        }
}

// ---------------------------------------------------------------- output
// out[b][t][o] = hist[t+1][b] . lin_W[o] + lin_b[o],  t in [0,10)
__global__ __launch_bounds__(256) void out_kernel(
    const unsigned short* __restrict__ hist,  // [11][B][256] bf16
    const float* __restrict__ linW,           // [4][256] fp32
    const float* __restrict__ linb,           // [4] fp32
    float* __restrict__ out)                  // [B][S][4] fp32
{
    int gid = blockIdx.x * 256 + threadIdx.x;
    if (gid >= B_SZ * DSTEPS * 4) return;
    int o = gid & 3;
    int pairId = gid >> 2;
    int row = pairId / DSTEPS;
    int t = pairId - row * DSTEPS;
    const unsigned short* hp = hist + ((size_t)(t + 1)) * B_SZ * DH + (size_t)row * DH;
    const float* wp = linW + o * DH;
    float acc = 0.f;
    for (int k8 = 0; k8 < DH / 8; ++k8) {
        v8s hv = *(const v8s*)&hp[k8 * 8];
        #pragma unroll
        for (int j = 0; j < 8; ++j)
            acc += bf2f((unsigned short)hv[j]) * wp[k8 * 8 + j];
    }
    out[(size_t)row * (S_SZ * 4) + t * 4 + o] = acc + linb[o];
}

// ---------------------------------------------------------------- launch
extern "C" void kernel_launch(void* const* d_in, const int* in_sizes, int n_in,
                              void* d_out, int out_size, void* d_ws, size_t ws_size,
                              hipStream_t stream)
{
    const float* x    = (const float*)d_in[0];
    const float* y    = (const float*)d_in[1];
    const float* eWih = (const float*)d_in[2];
    const float* eWhh = (const float*)d_in[3];
    const float* ebih = (const float*)d_in[4];
    const float* ebhh = (const float*)d_in[5];
    const float* dWih = (const float*)d_in[6];
    const float* dWhh = (const float*)d_in[7];
    const float* dbih = (const float*)d_in[8];
    const float* dbhh = (const float*)d_in[9];
    const float* linW = (const float*)d_in[10];
    const float* linb = (const float*)d_in[11];
    float* out = (float*)d_out;

    char* ws = (char*)d_ws;
    // ws layout (bytes):
    //   wihp     @ 0       : 768*136*2   = 208896
    //   eWhh_bf  @ 208896  : 384*128*2   =  98304   -> 307200
    //   eWih_bf  @ 307200  : 384*5*2     =   3840   -> 311296 (pad to 16B)
    //   dWhh_bf  @ 311296  : 768*256*2   = 393216   -> 704512
    //   ctex     @ 704512  : 4096*128*2  = 1048576  -> 1753088
    //   gib      @ 1753088 : 4096*768*2  = 6291456  -> 8044544
    //   hist     @ 8044544 : 11*4096*256*2 = 23068672 -> 31113216
    unsigned short* wihp    = (unsigned short*)(ws);
    unsigned short* eWhh_bf = (unsigned short*)(ws + 208896);
    unsigned short* eWih_bf = (unsigned short*)(ws + 307200);
    unsigned short* dWhh_bf = (unsigned short*)(ws + 311296);
    unsigned short* ctex    = (unsigned short*)(ws + 704512);
    unsigned short* gib     = (unsigned short*)(ws + 1753088);
    unsigned short* hist    = (unsigned short*)(ws + 8044544);

    prep_kernel<<<2048, 256, 0, stream>>>(dWih, eWhh, eWih, dWhh,
                                          wihp, eWhh_bf, eWih_bf, dWhh_bf,
                                          hist, out);
    enc_kernel<<<256, 512, 0, stream>>>(x, eWih_bf, eWhh_bf, ebih, ebhh, ctex);
    gib_kernel<<<dim3(64, 12), 256, 0, stream>>>(ctex, wihp, dbih, gib);
    for (int t = 0; t < DSTEPS; ++t) {
        dec_kernel<<<dim3(32, 8), 256, 0, stream>>>(
            dWhh_bf, dWih, dbhh, y, gib,
            hist + (size_t)t * B_SZ * DH,
            hist + (size_t)(t + 1) * B_SZ * DH, t);
    }
    out_kernel<<<640, 256, 0, stream>>>(hist, linW, linb, out);
}

// Round 3
// 339.086 us; speedup vs baseline: 1.0003x; 1.0003x over previous
//
#include <hip/hip_runtime.h>

#define B_SZ 4096
#define S_SZ 128
#define XD 5
#define EH 128
#define DH 256
#define DSTEPS 10

typedef short v8s __attribute__((ext_vector_type(8)));
typedef float v4f __attribute__((ext_vector_type(4)));

__device__ __forceinline__ float bf2f(unsigned short u) {
    union { unsigned int i; float f; } v; v.i = ((unsigned int)u) << 16; return v.f;
}
__device__ __forceinline__ unsigned short f2bf(float f) {
    union { float f; unsigned int i; } v; v.f = f;
    unsigned int x = v.i;
    return (unsigned short)((x + 0x7FFFu + ((x >> 16) & 1u)) >> 16);
}
__device__ __forceinline__ float fexp2(float x) { return __builtin_amdgcn_exp2f(x); }
__device__ __forceinline__ float frcp(float x) { return __builtin_amdgcn_rcpf(x); }
__device__ __forceinline__ float sigmoidf_(float x) {
    return frcp(1.f + fexp2(-1.44269504088896f * x));
}
__device__ __forceinline__ float tanhf_(float x) {
    float e = fexp2(2.88539008177793f * x);   // e^(2x)
    return 1.f - 2.f * frcp(e + 1.f);
}

// ---------------------------------------------------------------- prep
// Converts fp32 weights -> bf16 workspace copies, inits hist0=1, pads out.
__global__ void prep_kernel(const float* __restrict__ dWih,   // [768][129]
                            const float* __restrict__ eWhh,   // [384][128]
                            const float* __restrict__ eWih,   // [384][5]
                            const float* __restrict__ dWhh,   // [768][256]
                            unsigned short* __restrict__ wihp,     // [768][136] bf16
                            unsigned short* __restrict__ eWhh_bf,  // [384][128] bf16
                            unsigned short* __restrict__ eWih_bf,  // [384][5]  bf16
                            unsigned short* __restrict__ dWhh_bf,  // [768][256] bf16
                            unsigned short* __restrict__ hist0,    // [B][256] bf16
                            float* __restrict__ out)               // [B][S][4] fp32
{
    const unsigned short ONE = 0x3F80;
    const int NW  = 768 * 136;      // wihp
    const int NE1 = 384 * 128;      // eWhh
    const int NE2 = 384 * 5;        // eWih
    const int ND  = 768 * 256;      // dWhh
    const int NH  = B_SZ * DH;      // hist0
    const int NO  = B_SZ * S_SZ * 4;
    const int total = NW + NE1 + NE2 + ND + NH + NO;
    for (int i = blockIdx.x * 256 + threadIdx.x; i < total; i += gridDim.x * 256) {
        int idx = i;
        if (idx < NW) {
            int col = idx / 136, k = idx - col * 136;
            wihp[idx] = (k < 129) ? f2bf(dWih[col * 129 + k]) : (unsigned short)0;
            continue;
        }
        idx -= NW;
        if (idx < NE1) { eWhh_bf[idx] = f2bf(eWhh[idx]); continue; }
        idx -= NE1;
        if (idx < NE2) { eWih_bf[idx] = f2bf(eWih[idx]); continue; }
        idx -= NE2;
        if (idx < ND)  { dWhh_bf[idx] = f2bf(dWhh[idx]); continue; }
        idx -= ND;
        if (idx < NH)  { hist0[idx] = ONE; continue; }
        idx -= NH;
        int s = (idx >> 2) & (S_SZ - 1);
        if (s >= DSTEPS) out[idx] = 1.0f;
    }
}

// ---------------------------------------------------------------- encoder
// 256 blocks x 512 threads (8 waves = exactly 2 waves/EU -> bounds (512,2)
// so the ~76 fragment VGPRs stay RESIDENT across all 128 steps; round-2's
// default bounds capped VGPR at 60 and re-fetched Whh every step = 3.2 GB
// of L2 traffic = the bottleneck).
__global__ __launch_bounds__(512, 2) void enc_kernel(
    const float* __restrict__ x,              // [B][S][5] fp32
    const unsigned short* __restrict__ Wih,   // [384][5]  bf16
    const unsigned short* __restrict__ Whh,   // [384][128] bf16
    const float* __restrict__ bih,            // [384] fp32
    const float* __restrict__ bhh,            // [384] fp32
    unsigned short* __restrict__ ctex)        // [B][128] bf16
{
    __shared__ unsigned short xs[S_SZ][16][8];     // 32 KB
    __shared__ unsigned short hb[2][16][136];      // 8.5 KB, +8 pad
    __shared__ unsigned short zpad[8];

    const int tid = threadIdx.x;
    const int wv = tid >> 6;
    const int lane = tid & 63;
    const int n = lane & 15;
    const int kg = lane >> 4;       // K-group / C-row quad
    const int r0 = blockIdx.x * 16;

    for (int i = tid; i < 2 * 16 * 136; i += 512) ((unsigned short*)hb)[i] = 0;
    if (tid < 8) zpad[tid] = 0;
    for (int i = tid; i < 16 * S_SZ * 8; i += 512) {
        int m = i >> 10;            // / (128*8)
        int rem = i & 1023;
        int t = rem >> 3;
        int j = rem & 7;
        unsigned short v = 0;
        if (j < XD) v = f2bf(x[(size_t)(r0 + m) * (S_SZ * XD) + t * XD + j]);
        xs[t][m][j] = v;
    }

    const int colw = wv * 16 + n;   // this lane's column within H
    v8s fw[3][4];                   // Whh B-frags [gate][K-tile]
    v8s fx[3];                      // Wih B-frags [gate]
    #pragma unroll
    for (int g = 0; g < 3; ++g) {
        int gcol = g * EH + colw;
        #pragma unroll
        for (int kt = 0; kt < 4; ++kt)
            fw[g][kt] = *(const v8s*)&Whh[gcol * EH + kt * 32 + kg * 8];
        v8s t = {0, 0, 0, 0, 0, 0, 0, 0};
        if (kg == 0) {
            const unsigned short* p = &Wih[gcol * XD];
            #pragma unroll
            for (int j = 0; j < XD; ++j) t[j] = (short)p[j];
        }
        fx[g] = t;
    }
    const float b_r  = bih[colw]          + bhh[colw];
    const float b_z  = bih[EH + colw]     + bhh[EH + colw];
    const float bi_n = bih[2 * EH + colw];
    const float bh_n = bhh[2 * EH + colw];

    float hst[4] = {0.f, 0.f, 0.f, 0.f};
    __syncthreads();

    #pragma unroll 2
    for (int t = 0; t < S_SZ; ++t) {
        const int p = t & 1;
        v8s a[4];
        #pragma unroll
        for (int kt = 0; kt < 4; ++kt)
            a[kt] = *(const v8s*)&hb[p][n][kt * 32 + kg * 8];
        const unsigned short* xsrc = (kg == 0) ? &xs[t][n][0] : &zpad[0];
        v8s ax = *(const v8s*)xsrc;

        v4f accr  = {b_r, b_r, b_r, b_r};
        v4f accz  = {b_z, b_z, b_z, b_z};
        v4f acchn = {bh_n, bh_n, bh_n, bh_n};
        v4f accin = {bi_n, bi_n, bi_n, bi_n};
        #pragma unroll
        for (int kt = 0; kt < 4; ++kt) {
            accr  = __builtin_amdgcn_mfma_f32_16x16x32_bf16(a[kt], fw[0][kt], accr, 0, 0, 0);
            accz  = __builtin_amdgcn_mfma_f32_16x16x32_bf16(a[kt], fw[1][kt], accz, 0, 0, 0);
            acchn = __builtin_amdgcn_mfma_f32_16x16x32_bf16(a[kt], fw[2][kt], acchn, 0, 0, 0);
        }
        accr  = __builtin_amdgcn_mfma_f32_16x16x32_bf16(ax, fx[0], accr, 0, 0, 0);
        accz  = __builtin_amdgcn_mfma_f32_16x16x32_bf16(ax, fx[1], accz, 0, 0, 0);
        accin = __builtin_amdgcn_mfma_f32_16x16x32_bf16(ax, fx[2], accin, 0, 0, 0);

        #pragma unroll
        for (int e = 0; e < 4; ++e) {
            float r = sigmoidf_(accr[e]);
            float z = sigmoidf_(accz[e]);
            float nn = tanhf_(accin[e] + r * acchn[e]);
            float h = (1.f - z) * nn + z * hst[e];
            hst[e] = h;
            hb[1 - p][kg * 4 + e][colw] = f2bf(h);
        }
        __syncthreads();
    }
    #pragma unroll
    for (int e = 0; e < 4; ++e)
        ctex[(size_t)(r0 + kg * 4 + e) * EH + colw] = f2bf(hst[e]);
}

// ---------------------------------------------------------------- gi_base
// gib[b][768] = contex @ dec_Wih[:, :128].T + dec_bih   (bf16 out)
__global__ __launch_bounds__(256, 1) void gib_kernel(
    const unsigned short* __restrict__ ctex,   // [B][128] bf16
    const unsigned short* __restrict__ wihp,   // [768][136] bf16
    const float* __restrict__ dbih,            // [768] fp32
    unsigned short* __restrict__ gib)          // [B][768] bf16
{
    const int tid = threadIdx.x;
    const int wv = tid >> 6, lane = tid & 63, n = lane & 15, kg = lane >> 4;
    const int rb = blockIdx.x * 64 + wv * 16;
    const int cb = blockIdx.y * 64;

    v8s a[4];
    #pragma unroll
    for (int kt = 0; kt < 4; ++kt)
        a[kt] = *(const v8s*)&ctex[(size_t)(rb + n) * EH + kt * 32 + kg * 8];

    #pragma unroll
    for (int nt = 0; nt < 4; ++nt) {
        int col = cb + nt * 16 + n;
        float bb = dbih[col];
        v4f acc = {bb, bb, bb, bb};
        #pragma unroll
        for (int kt = 0; kt < 4; ++kt) {
            v8s b = *(const v8s*)&wihp[col * 136 + kt * 32 + kg * 8];
            acc = __builtin_amdgcn_mfma_f32_16x16x32_bf16(a[kt], b, acc, 0, 0, 0);
        }
        #pragma unroll
        for (int e = 0; e < 4; ++e)
            gib[(size_t)(rb + kg * 4 + e) * 768 + col] = f2bf(acc[e]);
    }
}

// ---------------------------------------------------------------- decoder step
// grid (32, 8): M=128 rows/block, 32 cols per gate per block (chunk).
// Whh chunk (96 rows x 256 K bf16 = 48KB) staged in LDS, shared by 4 waves.
__global__ __launch_bounds__(256, 1) void dec_kernel(
    const unsigned short* __restrict__ dWhh,   // [768][256] bf16
    const float* __restrict__ dWih,            // [768][129] fp32 (col 128 = y weight)
    const float* __restrict__ dbhh,            // [768] fp32
    const float* __restrict__ y,               // [B][128] fp32
    const unsigned short* __restrict__ gib,    // [B][768] bf16
    const unsigned short* __restrict__ histp,  // h_t   [B][256] bf16
    unsigned short* __restrict__ histn,        // h_t+1 [B][256] bf16
    int t)
{
    __shared__ unsigned short wsh[96][264];    // +8 pad
    const int tid = threadIdx.x;
    const int wv = tid >> 6, lane = tid & 63, n = lane & 15, kg = lane >> 4;
    const int rb = blockIdx.x * 128;
    const int cb = blockIdx.y * 32;
    const int rw = rb + wv * 32;

    for (int cid = tid; cid < 96 * 32; cid += 256) {
        int lr = cid >> 5;
        int off = (cid & 31) * 8;
        int grow = (lr >> 5) * DH + cb + (lr & 31);
        *(uint4*)&wsh[lr][off] = *(const uint4*)&dWhh[(size_t)grow * DH + off];
    }
    __syncthreads();

    float bR[2], bZ[2], bN[2], wyR[2], wyZ[2], wyN[2];
    #pragma unroll
    for (int ct = 0; ct < 2; ++ct) {
        int lc = cb + ct * 16 + n;
        bR[ct] = dbhh[lc];
        bZ[ct] = dbhh[DH + lc];
        bN[ct] = dbhh[2 * DH + lc];
        wyR[ct] = dWih[(size_t)lc * 129 + 128];
        wyZ[ct] = dWih[(size_t)(DH + lc) * 129 + 128];
        wyN[ct] = dWih[(size_t)(2 * DH + lc) * 129 + 128];
    }

    v4f acc[3][2][2];   // [gate][ct][mt]
    #pragma unroll
    for (int g = 0; g < 3; ++g)
        #pragma unroll
        for (int ct = 0; ct < 2; ++ct) {
            float bb = (g == 0) ? bR[ct] : ((g == 1) ? bZ[ct] : bN[ct]);
            acc[g][ct][0] = (v4f){bb, bb, bb, bb};
            acc[g][ct][1] = (v4f){bb, bb, bb, bb};
        }

    for (int kt = 0; kt < 8; ++kt) {
        v8s a0 = *(const v8s*)&histp[(size_t)(rw + n) * DH + kt * 32 + kg * 8];
        v8s a1 = *(const v8s*)&histp[(size_t)(rw + 16 + n) * DH + kt * 32 + kg * 8];
        #pragma unroll
        for (int g = 0; g < 3; ++g)
            #pragma unroll
            for (int ct = 0; ct < 2; ++ct) {
                v8s b = *(const v8s*)&wsh[g * 32 + ct * 16 + n][kt * 32 + kg * 8];
                acc[g][ct][0] = __builtin_amdgcn_mfma_f32_16x16x32_bf16(a0, b, acc[g][ct][0], 0, 0, 0);
                acc[g][ct][1] = __builtin_amdgcn_mfma_f32_16x16x32_bf16(a1, b, acc[g][ct][1], 0, 0, 0);
            }
    }

    #pragma unroll
    for (int mt = 0; mt < 2; ++mt)
        #pragma unroll
        for (int ct = 0; ct < 2; ++ct) {
            int lc = cb + ct * 16 + n;
            #pragma unroll
            for (int e = 0; e < 4; ++e) {
                int row = rw + mt * 16 + kg * 4 + e;
                float yv = y[(size_t)row * S_SZ + t];
                float giR = bf2f(gib[(size_t)row * 768 + lc]) + yv * wyR[ct];
                float giZ = bf2f(gib[(size_t)row * 768 + DH + lc]) + yv * wyZ[ct];
                float giN = bf2f(gib[(size_t)row * 768 + 2 * DH + lc]) + yv * wyN[ct];
                float r = sigmoidf_(giR + acc[0][ct][mt][e]);
                float z = sigmoidf_(giZ + acc[1][ct][mt][e]);
                float nn = tanhf_(giN + r * acc[2][ct][mt][e]);
                float hold = bf2f(histp[(size_t)row * DH + lc]);
                float h = (1.f - z) * nn + z * hold;
                histn[(size_t)row * DH + lc] = f2bf(h);
            }
        }
}

// ---------------------------------------------------------------- output
// out[b][t][o] = hist[t+1][b] . lin_W[o] + lin_b[o],  t in [0,10)
__global__ __launch_bounds__(256) void out_kernel(
    const unsigned short* __restrict__ hist,  // [11][B][256] bf16
    const float* __restrict__ linW,           // [4][256] fp32
    const float* __restrict__ linb,           // [4] fp32
    float* __restrict__ out)                  // [B][S][4] fp32
{
    int gid = blockIdx.x * 256 + threadIdx.x;
    if (gid >= B_SZ * DSTEPS * 4) return;
    int o = gid & 3;
    int pairId = gid >> 2;
    int row = pairId / DSTEPS;
    int t = pairId - row * DSTEPS;
    const unsigned short* hp = hist + ((size_t)(t + 1)) * B_SZ * DH + (size_t)row * DH;
    const float* wp = linW + o * DH;
    float acc = 0.f;
    for (int k8 = 0; k8 < DH / 8; ++k8) {
        v8s hv = *(const v8s*)&hp[k8 * 8];
        #pragma unroll
        for (int j = 0; j < 8; ++j)
            acc += bf2f((unsigned short)hv[j]) * wp[k8 * 8 + j];
    }
    out[(size_t)row * (S_SZ * 4) + t * 4 + o] = acc + linb[o];
}

// ---------------------------------------------------------------- launch
extern "C" void kernel_launch(void* const* d_in, const int* in_sizes, int n_in,
                              void* d_out, int out_size, void* d_ws, size_t ws_size,
                              hipStream_t stream)
{
    const float* x    = (const float*)d_in[0];
    const float* y    = (const float*)d_in[1];
    const float* eWih = (const float*)d_in[2];
    const float* eWhh = (const float*)d_in[3];
    const float* ebih = (const float*)d_in[4];
    const float* ebhh = (const float*)d_in[5];
    const float* dWih = (const float*)d_in[6];
    const float* dWhh = (const float*)d_in[7];
    const float* dbih = (const float*)d_in[8];
    const float* dbhh = (const float*)d_in[9];
    const float* linW = (const float*)d_in[10];
    const float* linb = (const float*)d_in[11];
    float* out = (float*)d_out;

    char* ws = (char*)d_ws;
    // ws layout (bytes):
    //   wihp     @ 0       : 768*136*2   = 208896
    //   eWhh_bf  @ 208896  : 384*128*2   =  98304   -> 307200
    //   eWih_bf  @ 307200  : 384*5*2     =   3840   -> 311296 (pad to 16B)
    //   dWhh_bf  @ 311296  : 768*256*2   = 393216   -> 704512
    //   ctex     @ 704512  : 4096*128*2  = 1048576  -> 1753088
    //   gib      @ 1753088 : 4096*768*2  = 6291456  -> 8044544
    //   hist     @ 8044544 : 11*4096*256*2 = 23068672 -> 31113216
    unsigned short* wihp    = (unsigned short*)(ws);
    unsigned short* eWhh_bf = (unsigned short*)(ws + 208896);
    unsigned short* eWih_bf = (unsigned short*)(ws + 307200);
    unsigned short* dWhh_bf = (unsigned short*)(ws + 311296);
    unsigned short* ctex    = (unsigned short*)(ws + 704512);
    unsigned short* gib     = (unsigned short*)(ws + 1753088);
    unsigned short* hist    = (unsigned short*)(ws + 8044544);

    prep_kernel<<<2048, 256, 0, stream>>>(dWih, eWhh, eWih, dWhh,
                                          wihp, eWhh_bf, eWih_bf, dWhh_bf,
                                          hist, out);
    enc_kernel<<<256, 512, 0, stream>>>(x, eWih_bf, eWhh_bf, ebih, ebhh, ctex);
    gib_kernel<<<dim3(64, 12), 256, 0, stream>>>(ctex, wihp, dbih, gib);
    for (int t = 0; t < DSTEPS; ++t) {
        dec_kernel<<<dim3(32, 8), 256, 0, stream>>>(
            dWhh_bf, dWih, dbhh, y, gib,
            hist + (size_t)t * B_SZ * DH,
            hist + (size_t)(t + 1) * B_SZ * DH, t);
    }
    out_kernel<<<640, 256, 0, stream>>>(hist, linW, linb, out);
}